// Round 5
// baseline (319.967 us; speedup 1.0000x reference)
//
#include <hip/hip_runtime.h>

// BKT 2-state HMM forward-backward. Zero-barrier, zero-spill, two-sweep.
// B=8192 chains, T=1024. One chain per wave (64 lanes = 64 chunks of KC=16).
// GG=4 chains/block (256 threads), grid 2048.
//
// Per wave (fully independent, NO __syncthreads):
//  P1: obs/corr -> regs (single HBM read); per-lane chunk composite F
//      (softplus recomputed per phase -- registers are the scarce resource,
//       transcendentals are not).
//  P2: dual Kogge-Stone scan over lanes (log-semiring 2x2 compose;
//      beta suffix uses F^T only: Bw-suffix == L^T * (F^T-suffix) since
//      L's columns are lse-normalized).
//  P3: forward sweep: pred -> staged LDS -> NT writeout; posteriors ps[32]
//      kept in REGISTERS and also staged/written per half.
//  P4: backward sweep: smoothed = ps + running beta -> staged -> writeout.
// Single 16 KB LDS staging buffer reused for all 6 half-stream writeouts
// (wave-local, DS ops are in-order per wave). ~105 VGPR live, cap 128:
// no scratch. Occupancy VGPR-capped at 4 waves/SIMD = 16 waves/CU.

#define BB 8192
#define TT 1024
#define KC 16               // steps per chunk
#define NC 64               // chunks per chain == lanes per wave
#define GG 4                // chains per block (1 per wave)
#define NTHREADS (GG * NC)  // 256
#define NEGI (-1.0e30f)     // log-domain "-inf" (safe under adds)

typedef float floatx4 __attribute__((ext_vector_type(4)));

__device__ __forceinline__ float softplusf(float x) {
    return fmaxf(x, 0.0f) + __logf(1.0f + __expf(-fabsf(x)));
}
__device__ __forceinline__ float lse2(float a, float b) {
    float m = fmaxf(a, b);
    return m + __logf(1.0f + __expf(-fabsf(a - b)));
}

__global__ __launch_bounds__(NTHREADS, 4) void bkt_kernel(
        const int* __restrict__ corr,
        const float* __restrict__ dyn,
        const float* __restrict__ obs,
        float* __restrict__ out) {
    // Single half-chunk staging buffer: [chain][chunk][4 pair-slots]. 16 KB.
    __shared__ floatx4 st[GG][NC][4];

    const int tid = threadIdx.x;
    const int g = tid >> 6;          // chain within block == wave id
    const int c = tid & (NC - 1);    // chunk index == lane
    const int b = blockIdx.x * GG + g;

    const float d0 = dyn[b * 3 + 0];
    const float d1 = dyn[b * 3 + 1];
    const float d2 = dyn[b * 3 + 2];
    const float sd0 = softplusf(d0), sd1 = softplusf(d1);
    // log_t[i][j]: column-softmax of [[0,d1],[d0,0]] (lse over i of col = 0)
    const float lt00 = -sd0, lt10 = d0 - sd0, lt01 = d1 - sd1, lt11 = -sd1;

    const long long cb = (long long)b * TT + c * KC;  // chunk base (float2 idx)
    const float2* obs2 = (const float2*)obs;
    const long long S4 = (long long)BB * 512;         // float4 per stream
    floatx4* o0 = (floatx4*)out;        // pred logprobs
    floatx4* o1 = o0 + S4;              // state posteriors (log-joint)
    floatx4* o2 = o1 + S4;              // smoothed

    // ---------------- P1: load to regs + fwd chunk composite -----------------
    float ox[16], oy[16];
    unsigned ybits = 0;
    float F00, F01, F10, F11;
    {
        const float4* op = (const float4*)(obs2 + cb);
        const int4* yp = (const int4*)(corr + cb);
        #pragma unroll
        for (int j = 0; j < 8; ++j) {
            float4 o4 = op[j];
            ox[2 * j] = o4.x; oy[2 * j] = o4.y;
            ox[2 * j + 1] = o4.z; oy[2 * j + 1] = o4.w;
        }
        #pragma unroll
        for (int j = 0; j < 4; ++j) {
            int4 y4 = yp[j];
            ybits |= (unsigned)(y4.x & 1) << (4 * j + 0);
            ybits |= (unsigned)(y4.y & 1) << (4 * j + 1);
            ybits |= (unsigned)(y4.z & 1) << (4 * j + 2);
            ybits |= (unsigned)(y4.w & 1) << (4 * j + 3);
        }
        #pragma unroll
        for (int q = 0; q < 16; ++q) {
            float sp0 = softplusf(ox[q]), sp1 = softplusf(oy[q]);
            int y = (ybits >> q) & 1;
            float py0 = y ? (ox[q] - sp0) : (-sp0);
            float py1 = y ? (-sp1) : (oy[q] - sp1);
            float N00 = py0 + lt00, N01 = py1 + lt01;
            float N10 = py0 + lt10, N11 = py1 + lt11;
            if (q == 0) {
                F00 = N00; F01 = N01; F10 = N10; F11 = N11;
            } else {   // F := N * F
                float a_ = lse2(N00 + F00, N01 + F10);
                float b_ = lse2(N00 + F01, N01 + F11);
                float c_ = lse2(N10 + F00, N11 + F10);
                float d_ = lse2(N10 + F01, N11 + F11);
                F00 = a_; F01 = b_; F10 = c_; F11 = d_;
            }
        }
    }

    // ---------------- P2: dual Kogge-Stone scan over lanes -------------------
    float G00 = F00, G01 = F01, G10 = F10, G11 = F11;
    float H00 = __shfl_down(F00, 1);
    float H01 = __shfl_down(F10, 1);   // transpose while shuffling
    float H10 = __shfl_down(F01, 1);
    float H11 = __shfl_down(F11, 1);
    if (c == NC - 1) { H00 = 0.0f; H01 = NEGI; H10 = NEGI; H11 = 0.0f; }
    #pragma unroll
    for (int dlv = 0; dlv < 6; ++dlv) {
        const int off = 1 << dlv;
        float u00 = __shfl_up(G00, off), u01 = __shfl_up(G01, off);
        float u10 = __shfl_up(G10, off), u11 = __shfl_up(G11, off);
        float g00 = lse2(G00 + u00, G01 + u10);
        float g01 = lse2(G00 + u01, G01 + u11);
        float g10 = lse2(G10 + u00, G11 + u10);
        float g11 = lse2(G10 + u01, G11 + u11);
        bool dg = (c >= off);
        G00 = dg ? g00 : G00; G01 = dg ? g01 : G01;
        G10 = dg ? g10 : G10; G11 = dg ? g11 : G11;
        float v00 = __shfl_down(H00, off), v01 = __shfl_down(H01, off);
        float v10 = __shfl_down(H10, off), v11 = __shfl_down(H11, off);
        float h00 = lse2(H00 + v00, H01 + v10);
        float h01 = lse2(H00 + v01, H01 + v11);
        float h10 = lse2(H10 + v00, H11 + v10);
        float h11 = lse2(H10 + v01, H11 + v11);
        bool dh = (c + off < NC);
        H00 = dh ? h00 : H00; H01 = dh ? h01 : H01;
        H10 = dh ? h10 : H10; H11 = dh ? h11 : H11;
    }
    // alpha at chunk entry: P_{c-1} * a_init (lane 0: a_init).
    const float sd2 = softplusf(d2);
    const float ai0 = -sd2, ai1 = d2 - sd2;
    float P00 = __shfl_up(G00, 1), P01 = __shfl_up(G01, 1);
    float P10 = __shfl_up(G10, 1), P11 = __shfl_up(G11, 1);
    float t0 = lse2(P00 + ai0, P01 + ai1);
    float t1 = lse2(P10 + ai0, P11 + ai1);
    float a0 = (c == 0) ? ai0 : t0;
    float a1 = (c == 0) ? ai1 : t1;
    // beta at chunk end: L^T * (row-lse of H)
    float w0 = lse2(H00, H01);
    float w1 = lse2(H10, H11);
    float be0 = lse2(lt00 + w0, lt10 + w1);
    float be1 = lse2(lt01 + w0, lt11 + w1);

    const long long bb4 = (long long)b * 512;   // float4 base of this chain
    const int kswz = (c >> 1) & 3;

    // ---------------- P3: forward sweep: pred + posteriors -------------------
    float ps[32];   // posteriors (log-joint), kept for P4
    #pragma unroll
    for (int h = 0; h < 2; ++h) {
        float e0a, e1a;   // even-step saved pred pair
        #pragma unroll
        for (int l = 0; l < 8; ++l) {
            const int q = h * 8 + l;
            float sp0 = softplusf(ox[q]), sp1 = softplusf(oy[q]);
            float lo00 = -sp0,        lo01 = ox[q] - sp0;
            float lo10 = oy[q] - sp1, lo11 = -sp1;
            float p0 = lse2(lo00 + a0, lo10 + a1);
            float p1 = lse2(lo01 + a0, lo11 + a1);
            float n = lse2(p0, p1);
            float wo0 = p0 - n, wo1 = p1 - n;
            int y = (ybits >> q) & 1;
            float py0 = y ? lo01 : lo00;
            float py1 = y ? lo11 : lo10;
            float s0 = py0 + a0, s1 = py1 + a1;
            ps[2 * q] = s0; ps[2 * q + 1] = s1;
            a0 = lse2(s0 + lt00, s1 + lt01);
            a1 = lse2(s0 + lt10, s1 + lt11);
            if (l & 1) {
                st[g][c][(l >> 1) ^ kswz] = (floatx4){e0a, e1a, wo0, wo1};
            } else { e0a = wo0; e1a = wo1; }
        }
        // writeout pred half h (wave-local coalesced, NT)
        #pragma unroll
        for (int i = 0; i < 4; ++i) {
            int flat = i * 64 + c;
            int c2 = flat >> 2, k2 = flat & 3;
            floatx4 v = st[g][c2][k2 ^ ((c2 >> 1) & 3)];
            __builtin_nontemporal_store(
                v, o0 + bb4 + (long long)(c2 * 8 + k2 + 4 * h));
        }
        // stage + writeout posterior half h from ps regs
        #pragma unroll
        for (int k = 0; k < 4; ++k)
            st[g][c][k ^ kswz] = (floatx4){ps[16 * h + 4 * k], ps[16 * h + 4 * k + 1],
                                           ps[16 * h + 4 * k + 2], ps[16 * h + 4 * k + 3]};
        #pragma unroll
        for (int i = 0; i < 4; ++i) {
            int flat = i * 64 + c;
            int c2 = flat >> 2, k2 = flat & 3;
            floatx4 v = st[g][c2][k2 ^ ((c2 >> 1) & 3)];
            __builtin_nontemporal_store(
                v, o1 + bb4 + (long long)(c2 * 8 + k2 + 4 * h));
        }
    }

    // ---------------- P4: backward sweep: smoothed ---------------------------
    #pragma unroll
    for (int h = 1; h >= 0; --h) {
        float o0s, o1s;   // odd-step saved smoothed pair
        #pragma unroll
        for (int l = 7; l >= 0; --l) {
            const int q = h * 8 + l;
            // smoothed at q uses current beta (aligned at q)
            float u0 = ps[2 * q] + be0, u1 = ps[2 * q + 1] + be1;
            float nn = lse2(u0, u1);
            float w20 = u0 - nn, w21 = u1 - nn;
            // advance beta to q-1
            float sp0 = softplusf(ox[q]), sp1 = softplusf(oy[q]);
            int y = (ybits >> q) & 1;
            float py0 = y ? (ox[q] - sp0) : (-sp0);
            float py1 = y ? (-sp1) : (oy[q] - sp1);
            float nb0 = lse2(py0 + be0 + lt00, py1 + be1 + lt10);
            float nb1 = lse2(py0 + be0 + lt01, py1 + be1 + lt11);
            be0 = nb0; be1 = nb1;
            if (l & 1) { o0s = w20; o1s = w21; }
            else       st[g][c][(l >> 1) ^ kswz] = (floatx4){w20, w21, o0s, o1s};
        }
        #pragma unroll
        for (int i = 0; i < 4; ++i) {
            int flat = i * 64 + c;
            int c2 = flat >> 2, k2 = flat & 3;
            floatx4 v = st[g][c2][k2 ^ ((c2 >> 1) & 3)];
            __builtin_nontemporal_store(
                v, o2 + bb4 + (long long)(c2 * 8 + k2 + 4 * h));
        }
    }
}

extern "C" void kernel_launch(void* const* d_in, const int* in_sizes, int n_in,
                              void* d_out, int out_size, void* d_ws, size_t ws_size,
                              hipStream_t stream) {
    const int*   corr = (const int*)d_in[0];
    const float* dyn  = (const float*)d_in[1];
    const float* obs  = (const float*)d_in[2];
    float* out = (float*)d_out;

    dim3 block(NTHREADS);            // 256 = 4 chains x 64 chunks
    dim3 grid(BB / GG);              // 2048 blocks
    bkt_kernel<<<grid, block, 0, stream>>>(corr, dyn, obs, out);
}

// Round 6
// 317.450 us; speedup vs baseline: 1.0079x; 1.0079x over previous
//
#include <hip/hip_runtime.h>

// BKT 2-state HMM forward-backward. Zero-barrier, zero-spill, two-sweep.
// B=8192 chains, T=1024. One chain per wave (64 lanes = 64 chunks of KC=16).
// GG=4 chains/block (256 threads), grid 2048.
//
// Per wave (fully independent, NO __syncthreads):
//  P1: obs/corr -> regs (single HBM read); per-lane chunk composite F
//      (softplus recomputed per phase -- registers are the scarce resource,
//       transcendentals are not).
//  P2: dual Kogge-Stone scan over lanes (log-semiring 2x2 compose;
//      beta suffix uses F^T only: Bw-suffix == L^T * (F^T-suffix) since
//      L's columns are lse-normalized).
//  P3: forward sweep: pred -> staged LDS -> NT writeout; posteriors ps[32]
//      kept in REGISTERS and also staged/written per half.
//  P4: backward sweep: smoothed = ps + running beta -> staged -> writeout.
//
// KEY (round 6): amdgpu_waves_per_eu(4,4) pins the backend's occupancy
// target. __launch_bounds__(256,4) gave the RANGE (4,8); the allocator
// chased 8 waves/EU (64-VGPR budget) and spilled ~30 floats/thread to
// scratch -> +110 MB of dirty-scratch HBM evictions (round-5 counters).
// Exact (4,4) => firm 128-VGPR budget; live set ~91 VGPR => zero spill.

#define BB 8192
#define TT 1024
#define KC 16               // steps per chunk
#define NC 64               // chunks per chain == lanes per wave
#define GG 4                // chains per block (1 per wave)
#define NTHREADS (GG * NC)  // 256
#define NEGI (-1.0e30f)     // log-domain "-inf" (safe under adds)

typedef float floatx4 __attribute__((ext_vector_type(4)));

__device__ __forceinline__ float softplusf(float x) {
    return fmaxf(x, 0.0f) + __logf(1.0f + __expf(-fabsf(x)));
}
__device__ __forceinline__ float lse2(float a, float b) {
    float m = fmaxf(a, b);
    return m + __logf(1.0f + __expf(-fabsf(a - b)));
}

__global__ __attribute__((amdgpu_flat_work_group_size(NTHREADS, NTHREADS),
                          amdgpu_waves_per_eu(4, 4)))
void bkt_kernel(
        const int* __restrict__ corr,
        const float* __restrict__ dyn,
        const float* __restrict__ obs,
        float* __restrict__ out) {
    // Single half-chunk staging buffer: [chain][chunk][4 pair-slots]. 16 KB.
    __shared__ floatx4 st[GG][NC][4];

    const int tid = threadIdx.x;
    const int g = tid >> 6;          // chain within block == wave id
    const int c = tid & (NC - 1);    // chunk index == lane
    const int b = blockIdx.x * GG + g;

    const float d0 = dyn[b * 3 + 0];
    const float d1 = dyn[b * 3 + 1];
    const float d2 = dyn[b * 3 + 2];
    const float sd0 = softplusf(d0), sd1 = softplusf(d1);
    // log_t[i][j]: column-softmax of [[0,d1],[d0,0]] (lse over i of col = 0)
    const float lt00 = -sd0, lt10 = d0 - sd0, lt01 = d1 - sd1, lt11 = -sd1;

    const long long cb = (long long)b * TT + c * KC;  // chunk base (float2 idx)
    const float2* obs2 = (const float2*)obs;
    const long long S4 = (long long)BB * 512;         // float4 per stream
    floatx4* o0 = (floatx4*)out;        // pred logprobs
    floatx4* o1 = o0 + S4;              // state posteriors (log-joint)
    floatx4* o2 = o1 + S4;              // smoothed

    // ---------------- P1: load to regs + fwd chunk composite -----------------
    float ox[16], oy[16];
    unsigned ybits = 0;
    float F00, F01, F10, F11;
    {
        const float4* op = (const float4*)(obs2 + cb);
        const int4* yp = (const int4*)(corr + cb);
        #pragma unroll
        for (int j = 0; j < 8; ++j) {
            float4 o4 = op[j];
            ox[2 * j] = o4.x; oy[2 * j] = o4.y;
            ox[2 * j + 1] = o4.z; oy[2 * j + 1] = o4.w;
        }
        #pragma unroll
        for (int j = 0; j < 4; ++j) {
            int4 y4 = yp[j];
            ybits |= (unsigned)(y4.x & 1) << (4 * j + 0);
            ybits |= (unsigned)(y4.y & 1) << (4 * j + 1);
            ybits |= (unsigned)(y4.z & 1) << (4 * j + 2);
            ybits |= (unsigned)(y4.w & 1) << (4 * j + 3);
        }
        #pragma unroll
        for (int q = 0; q < 16; ++q) {
            float sp0 = softplusf(ox[q]), sp1 = softplusf(oy[q]);
            int y = (ybits >> q) & 1;
            float py0 = y ? (ox[q] - sp0) : (-sp0);
            float py1 = y ? (-sp1) : (oy[q] - sp1);
            float N00 = py0 + lt00, N01 = py1 + lt01;
            float N10 = py0 + lt10, N11 = py1 + lt11;
            if (q == 0) {
                F00 = N00; F01 = N01; F10 = N10; F11 = N11;
            } else {   // F := N * F
                float a_ = lse2(N00 + F00, N01 + F10);
                float b_ = lse2(N00 + F01, N01 + F11);
                float c_ = lse2(N10 + F00, N11 + F10);
                float d_ = lse2(N10 + F01, N11 + F11);
                F00 = a_; F01 = b_; F10 = c_; F11 = d_;
            }
        }
    }

    // ---------------- P2: dual Kogge-Stone scan over lanes -------------------
    float G00 = F00, G01 = F01, G10 = F10, G11 = F11;
    float H00 = __shfl_down(F00, 1);
    float H01 = __shfl_down(F10, 1);   // transpose while shuffling
    float H10 = __shfl_down(F01, 1);
    float H11 = __shfl_down(F11, 1);
    if (c == NC - 1) { H00 = 0.0f; H01 = NEGI; H10 = NEGI; H11 = 0.0f; }
    #pragma unroll
    for (int dlv = 0; dlv < 6; ++dlv) {
        const int off = 1 << dlv;
        float u00 = __shfl_up(G00, off), u01 = __shfl_up(G01, off);
        float u10 = __shfl_up(G10, off), u11 = __shfl_up(G11, off);
        float g00 = lse2(G00 + u00, G01 + u10);
        float g01 = lse2(G00 + u01, G01 + u11);
        float g10 = lse2(G10 + u00, G11 + u10);
        float g11 = lse2(G10 + u01, G11 + u11);
        bool dg = (c >= off);
        G00 = dg ? g00 : G00; G01 = dg ? g01 : G01;
        G10 = dg ? g10 : G10; G11 = dg ? g11 : G11;
        float v00 = __shfl_down(H00, off), v01 = __shfl_down(H01, off);
        float v10 = __shfl_down(H10, off), v11 = __shfl_down(H11, off);
        float h00 = lse2(H00 + v00, H01 + v10);
        float h01 = lse2(H00 + v01, H01 + v11);
        float h10 = lse2(H10 + v00, H11 + v10);
        float h11 = lse2(H10 + v01, H11 + v11);
        bool dh = (c + off < NC);
        H00 = dh ? h00 : H00; H01 = dh ? h01 : H01;
        H10 = dh ? h10 : H10; H11 = dh ? h11 : H11;
    }
    // alpha at chunk entry: P_{c-1} * a_init (lane 0: a_init).
    const float sd2 = softplusf(d2);
    const float ai0 = -sd2, ai1 = d2 - sd2;
    float P00 = __shfl_up(G00, 1), P01 = __shfl_up(G01, 1);
    float P10 = __shfl_up(G10, 1), P11 = __shfl_up(G11, 1);
    float t0 = lse2(P00 + ai0, P01 + ai1);
    float t1 = lse2(P10 + ai0, P11 + ai1);
    float a0 = (c == 0) ? ai0 : t0;
    float a1 = (c == 0) ? ai1 : t1;
    // beta at chunk end: L^T * (row-lse of H)
    float w0 = lse2(H00, H01);
    float w1 = lse2(H10, H11);
    float be0 = lse2(lt00 + w0, lt10 + w1);
    float be1 = lse2(lt01 + w0, lt11 + w1);

    const long long bb4 = (long long)b * 512;   // float4 base of this chain
    const int kswz = (c >> 1) & 3;

    // ---------------- P3: forward sweep: pred + posteriors -------------------
    float ps[32];   // posteriors (log-joint), kept for P4
    #pragma unroll
    for (int h = 0; h < 2; ++h) {
        float e0a, e1a;   // even-step saved pred pair
        #pragma unroll
        for (int l = 0; l < 8; ++l) {
            const int q = h * 8 + l;
            float sp0 = softplusf(ox[q]), sp1 = softplusf(oy[q]);
            float lo00 = -sp0,        lo01 = ox[q] - sp0;
            float lo10 = oy[q] - sp1, lo11 = -sp1;
            float p0 = lse2(lo00 + a0, lo10 + a1);
            float p1 = lse2(lo01 + a0, lo11 + a1);
            float n = lse2(p0, p1);
            float wo0 = p0 - n, wo1 = p1 - n;
            int y = (ybits >> q) & 1;
            float py0 = y ? lo01 : lo00;
            float py1 = y ? lo11 : lo10;
            float s0 = py0 + a0, s1 = py1 + a1;
            ps[2 * q] = s0; ps[2 * q + 1] = s1;
            a0 = lse2(s0 + lt00, s1 + lt01);
            a1 = lse2(s0 + lt10, s1 + lt11);
            if (l & 1) {
                st[g][c][(l >> 1) ^ kswz] = (floatx4){e0a, e1a, wo0, wo1};
            } else { e0a = wo0; e1a = wo1; }
        }
        // writeout pred half h (wave-local coalesced, NT)
        #pragma unroll
        for (int i = 0; i < 4; ++i) {
            int flat = i * 64 + c;
            int c2 = flat >> 2, k2 = flat & 3;
            floatx4 v = st[g][c2][k2 ^ ((c2 >> 1) & 3)];
            __builtin_nontemporal_store(
                v, o0 + bb4 + (long long)(c2 * 8 + k2 + 4 * h));
        }
        // stage + writeout posterior half h from ps regs
        #pragma unroll
        for (int k = 0; k < 4; ++k)
            st[g][c][k ^ kswz] = (floatx4){ps[16 * h + 4 * k], ps[16 * h + 4 * k + 1],
                                           ps[16 * h + 4 * k + 2], ps[16 * h + 4 * k + 3]};
        #pragma unroll
        for (int i = 0; i < 4; ++i) {
            int flat = i * 64 + c;
            int c2 = flat >> 2, k2 = flat & 3;
            floatx4 v = st[g][c2][k2 ^ ((c2 >> 1) & 3)];
            __builtin_nontemporal_store(
                v, o1 + bb4 + (long long)(c2 * 8 + k2 + 4 * h));
        }
    }

    // ---------------- P4: backward sweep: smoothed ---------------------------
    #pragma unroll
    for (int h = 1; h >= 0; --h) {
        float o0s, o1s;   // odd-step saved smoothed pair
        #pragma unroll
        for (int l = 7; l >= 0; --l) {
            const int q = h * 8 + l;
            // smoothed at q uses current beta (aligned at q)
            float u0 = ps[2 * q] + be0, u1 = ps[2 * q + 1] + be1;
            float nn = lse2(u0, u1);
            float w20 = u0 - nn, w21 = u1 - nn;
            // advance beta to q-1
            float sp0 = softplusf(ox[q]), sp1 = softplusf(oy[q]);
            int y = (ybits >> q) & 1;
            float py0 = y ? (ox[q] - sp0) : (-sp0);
            float py1 = y ? (-sp1) : (oy[q] - sp1);
            float nb0 = lse2(py0 + be0 + lt00, py1 + be1 + lt10);
            float nb1 = lse2(py0 + be0 + lt01, py1 + be1 + lt11);
            be0 = nb0; be1 = nb1;
            if (l & 1) { o0s = w20; o1s = w21; }
            else       st[g][c][(l >> 1) ^ kswz] = (floatx4){w20, w21, o0s, o1s};
        }
        #pragma unroll
        for (int i = 0; i < 4; ++i) {
            int flat = i * 64 + c;
            int c2 = flat >> 2, k2 = flat & 3;
            floatx4 v = st[g][c2][k2 ^ ((c2 >> 1) & 3)];
            __builtin_nontemporal_store(
                v, o2 + bb4 + (long long)(c2 * 8 + k2 + 4 * h));
        }
    }
}

extern "C" void kernel_launch(void* const* d_in, const int* in_sizes, int n_in,
                              void* d_out, int out_size, void* d_ws, size_t ws_size,
                              hipStream_t stream) {
    const int*   corr = (const int*)d_in[0];
    const float* dyn  = (const float*)d_in[1];
    const float* obs  = (const float*)d_in[2];
    float* out = (float*)d_out;

    dim3 block(NTHREADS);            // 256 = 4 chains x 64 chunks
    dim3 grid(BB / GG);              // 2048 blocks
    bkt_kernel<<<grid, block, 0, stream>>>(corr, dyn, obs, out);
}

// Round 7
// 300.677 us; speedup vs baseline: 1.0642x; 1.0558x over previous
//
#include <hip/hip_runtime.h>

// BKT 2-state HMM forward-backward. Zero-barrier, zero-spill, two-sweep.
// B=8192 chains, T=1024. One chain per wave (64 lanes = 64 chunks of KC=16).
// GG=4 chains/block (256 threads), grid 2048.
//
// Per wave (fully independent, NO __syncthreads):
//  P1: obs/corr -> regs (single HBM read); per-lane chunk composite F.
//  P2: dual Kogge-Stone scan over lanes (log-semiring 2x2 compose;
//      beta suffix uses F^T only: Bw-suffix == L^T * (F^T-suffix) since
//      L's columns are lse-normalized).
//  P3: forward sweep (16 steps): pred pairs staged to LDS -> full-chain
//      contiguous NT writeout; posteriors ps[32] kept in registers, then
//      staged+written the same way.
//  P4: backward sweep: smoothed = ps + running beta -> staged -> writeout.
//
// ROUND 7 KEY: LDS sized to 33.8 KB on purpose. LLVM's regalloc targets the
// LDS-limited occupancy: at 16 KB LDS it targeted 8 waves/EU => 64-VGPR
// budget => ~30 floats/thread spilled to scratch (+110 MB HBM write, r5/r6
// counters). 33.8 KB => 4 blocks/CU => 4 waves/EU target => 128-VGPR
// budget => zero spill, same 16 waves/CU occupancy.
// Writeout is full-chain contiguous (8 x 1KB NT stores per stream), fixing
// the half-line (64B-in-128B-line, two passes) write amplification of r5/r6.

#define BB 8192
#define TT 1024
#define KC 16               // steps per chunk
#define NC 64               // chunks per chain == lanes per wave
#define GG 4                // chains per block (1 per wave)
#define NTHREADS (GG * NC)  // 256
#define NEGI (-1.0e30f)     // log-domain "-inf" (safe under adds)

typedef float floatx4 __attribute__((ext_vector_type(4)));

__device__ __forceinline__ float softplusf(float x) {
    return fmaxf(x, 0.0f) + __logf(1.0f + __expf(-fabsf(x)));
}
__device__ __forceinline__ float lse2(float a, float b) {
    float m = fmaxf(a, b);
    return m + __logf(1.0f + __expf(-fabsf(a - b)));
}

__global__ __launch_bounds__(NTHREADS, 4) void bkt_kernel(
        const int* __restrict__ corr,
        const float* __restrict__ dyn,
        const float* __restrict__ obs,
        float* __restrict__ out) {
    // Full-chunk staging: [chain][chunk][8 pair-slots], +2 pad rows to push
    // LDS past 32 KB (forces 4 blocks/CU -> 128-VGPR regalloc budget).
    __shared__ floatx4 st[GG][NC + 2][8];   // 33792 B

    const int tid = threadIdx.x;
    const int g = tid >> 6;          // chain within block == wave id
    const int c = tid & (NC - 1);    // chunk index == lane
    const int b = blockIdx.x * GG + g;

    const float d0 = dyn[b * 3 + 0];
    const float d1 = dyn[b * 3 + 1];
    const float d2 = dyn[b * 3 + 2];
    const float sd0 = softplusf(d0), sd1 = softplusf(d1);
    // log_t[i][j]: column-softmax of [[0,d1],[d0,0]] (lse over i of col = 0)
    const float lt00 = -sd0, lt10 = d0 - sd0, lt01 = d1 - sd1, lt11 = -sd1;

    const long long cb = (long long)b * TT + c * KC;  // chunk base (float2 idx)
    const float2* obs2 = (const float2*)obs;
    const long long S4 = (long long)BB * 512;         // float4 per stream
    floatx4* o0 = (floatx4*)out;        // pred logprobs
    floatx4* o1 = o0 + S4;              // state posteriors (log-joint)
    floatx4* o2 = o1 + S4;              // smoothed

    // ---------------- P1: load to regs + fwd chunk composite -----------------
    float ox[16], oy[16];
    unsigned ybits = 0;
    float F00, F01, F10, F11;
    {
        const float4* op = (const float4*)(obs2 + cb);
        const int4* yp = (const int4*)(corr + cb);
        #pragma unroll
        for (int j = 0; j < 8; ++j) {
            float4 o4 = op[j];
            ox[2 * j] = o4.x; oy[2 * j] = o4.y;
            ox[2 * j + 1] = o4.z; oy[2 * j + 1] = o4.w;
        }
        #pragma unroll
        for (int j = 0; j < 4; ++j) {
            int4 y4 = yp[j];
            ybits |= (unsigned)(y4.x & 1) << (4 * j + 0);
            ybits |= (unsigned)(y4.y & 1) << (4 * j + 1);
            ybits |= (unsigned)(y4.z & 1) << (4 * j + 2);
            ybits |= (unsigned)(y4.w & 1) << (4 * j + 3);
        }
        #pragma unroll
        for (int q = 0; q < 16; ++q) {
            float sp0 = softplusf(ox[q]), sp1 = softplusf(oy[q]);
            int y = (ybits >> q) & 1;
            float py0 = y ? (ox[q] - sp0) : (-sp0);
            float py1 = y ? (-sp1) : (oy[q] - sp1);
            float N00 = py0 + lt00, N01 = py1 + lt01;
            float N10 = py0 + lt10, N11 = py1 + lt11;
            if (q == 0) {
                F00 = N00; F01 = N01; F10 = N10; F11 = N11;
            } else {   // F := N * F
                float a_ = lse2(N00 + F00, N01 + F10);
                float b_ = lse2(N00 + F01, N01 + F11);
                float c_ = lse2(N10 + F00, N11 + F10);
                float d_ = lse2(N10 + F01, N11 + F11);
                F00 = a_; F01 = b_; F10 = c_; F11 = d_;
            }
        }
    }

    // ---------------- P2: dual Kogge-Stone scan over lanes -------------------
    float G00 = F00, G01 = F01, G10 = F10, G11 = F11;
    float H00 = __shfl_down(F00, 1);
    float H01 = __shfl_down(F10, 1);   // transpose while shuffling
    float H10 = __shfl_down(F01, 1);
    float H11 = __shfl_down(F11, 1);
    if (c == NC - 1) { H00 = 0.0f; H01 = NEGI; H10 = NEGI; H11 = 0.0f; }
    #pragma unroll
    for (int dlv = 0; dlv < 6; ++dlv) {
        const int off = 1 << dlv;
        float u00 = __shfl_up(G00, off), u01 = __shfl_up(G01, off);
        float u10 = __shfl_up(G10, off), u11 = __shfl_up(G11, off);
        float g00 = lse2(G00 + u00, G01 + u10);
        float g01 = lse2(G00 + u01, G01 + u11);
        float g10 = lse2(G10 + u00, G11 + u10);
        float g11 = lse2(G10 + u01, G11 + u11);
        bool dg = (c >= off);
        G00 = dg ? g00 : G00; G01 = dg ? g01 : G01;
        G10 = dg ? g10 : G10; G11 = dg ? g11 : G11;
        float v00 = __shfl_down(H00, off), v01 = __shfl_down(H01, off);
        float v10 = __shfl_down(H10, off), v11 = __shfl_down(H11, off);
        float h00 = lse2(H00 + v00, H01 + v10);
        float h01 = lse2(H00 + v01, H01 + v11);
        float h10 = lse2(H10 + v00, H11 + v10);
        float h11 = lse2(H10 + v01, H11 + v11);
        bool dh = (c + off < NC);
        H00 = dh ? h00 : H00; H01 = dh ? h01 : H01;
        H10 = dh ? h10 : H10; H11 = dh ? h11 : H11;
    }
    // alpha at chunk entry: P_{c-1} * a_init (lane 0: a_init).
    const float sd2 = softplusf(d2);
    const float ai0 = -sd2, ai1 = d2 - sd2;
    float P00 = __shfl_up(G00, 1), P01 = __shfl_up(G01, 1);
    float P10 = __shfl_up(G10, 1), P11 = __shfl_up(G11, 1);
    float t0 = lse2(P00 + ai0, P01 + ai1);
    float t1 = lse2(P10 + ai0, P11 + ai1);
    float a0 = (c == 0) ? ai0 : t0;
    float a1 = (c == 0) ? ai1 : t1;
    // beta at chunk end: L^T * (row-lse of H)
    float w0 = lse2(H00, H01);
    float w1 = lse2(H10, H11);
    float be0 = lse2(lt00 + w0, lt10 + w1);
    float be1 = lse2(lt01 + w0, lt11 + w1);

    const long long bb4 = (long long)b * 512;   // float4 base of this chain
    const int sw = c & 7;                       // slot swizzle

    // ---------------- P3: forward sweep: pred + posteriors -------------------
    float ps[32];   // posteriors (log-joint), kept for P4
    {
        float e0a, e1a;   // even-step saved pred pair
        #pragma unroll
        for (int q = 0; q < 16; ++q) {
            float sp0 = softplusf(ox[q]), sp1 = softplusf(oy[q]);
            float lo00 = -sp0,        lo01 = ox[q] - sp0;
            float lo10 = oy[q] - sp1, lo11 = -sp1;
            float p0 = lse2(lo00 + a0, lo10 + a1);
            float p1 = lse2(lo01 + a0, lo11 + a1);
            float n = lse2(p0, p1);
            float wo0 = p0 - n, wo1 = p1 - n;
            int y = (ybits >> q) & 1;
            float py0 = y ? lo01 : lo00;
            float py1 = y ? lo11 : lo10;
            float s0 = py0 + a0, s1 = py1 + a1;
            ps[2 * q] = s0; ps[2 * q + 1] = s1;
            a0 = lse2(s0 + lt00, s1 + lt01);
            a1 = lse2(s0 + lt10, s1 + lt11);
            if (q & 1) st[g][c][(q >> 1) ^ sw] = (floatx4){e0a, e1a, wo0, wo1};
            else       { e0a = wo0; e1a = wo1; }
        }
    }
    // writeout pred: full chain, contiguous (8 x 1KB NT per wave)
    #pragma unroll
    for (int i = 0; i < 8; ++i) {
        int flat = i * 64 + c;            // float4 idx within chain [0,512)
        int c2 = flat >> 3, k2 = flat & 7;
        floatx4 v = st[g][c2][k2 ^ (c2 & 7)];
        __builtin_nontemporal_store(v, o0 + bb4 + flat);
    }
    // stage + writeout posteriors from ps regs
    #pragma unroll
    for (int k = 0; k < 8; ++k)
        st[g][c][k ^ sw] = (floatx4){ps[4 * k], ps[4 * k + 1],
                                     ps[4 * k + 2], ps[4 * k + 3]};
    #pragma unroll
    for (int i = 0; i < 8; ++i) {
        int flat = i * 64 + c;
        int c2 = flat >> 3, k2 = flat & 7;
        floatx4 v = st[g][c2][k2 ^ (c2 & 7)];
        __builtin_nontemporal_store(v, o1 + bb4 + flat);
    }

    // ---------------- P4: backward sweep: smoothed ---------------------------
    {
        float o0s, o1s;   // odd-step saved smoothed pair
        #pragma unroll
        for (int q = 15; q >= 0; --q) {
            // smoothed at q uses current beta (aligned at q)
            float u0 = ps[2 * q] + be0, u1 = ps[2 * q + 1] + be1;
            float nn = lse2(u0, u1);
            float w20 = u0 - nn, w21 = u1 - nn;
            // advance beta to q-1
            float sp0 = softplusf(ox[q]), sp1 = softplusf(oy[q]);
            int y = (ybits >> q) & 1;
            float py0 = y ? (ox[q] - sp0) : (-sp0);
            float py1 = y ? (-sp1) : (oy[q] - sp1);
            float nb0 = lse2(py0 + be0 + lt00, py1 + be1 + lt10);
            float nb1 = lse2(py0 + be0 + lt01, py1 + be1 + lt11);
            be0 = nb0; be1 = nb1;
            if (q & 1) { o0s = w20; o1s = w21; }
            else       st[g][c][(q >> 1) ^ sw] = (floatx4){w20, w21, o0s, o1s};
        }
    }
    #pragma unroll
    for (int i = 0; i < 8; ++i) {
        int flat = i * 64 + c;
        int c2 = flat >> 3, k2 = flat & 7;
        floatx4 v = st[g][c2][k2 ^ (c2 & 7)];
        __builtin_nontemporal_store(v, o2 + bb4 + flat);
    }
}

extern "C" void kernel_launch(void* const* d_in, const int* in_sizes, int n_in,
                              void* d_out, int out_size, void* d_ws, size_t ws_size,
                              hipStream_t stream) {
    const int*   corr = (const int*)d_in[0];
    const float* dyn  = (const float*)d_in[1];
    const float* obs  = (const float*)d_in[2];
    float* out = (float*)d_out;

    dim3 block(NTHREADS);            // 256 = 4 chains x 64 chunks
    dim3 grid(BB / GG);              // 2048 blocks
    bkt_kernel<<<grid, block, 0, stream>>>(corr, dyn, obs, out);
}

// Round 9
// 288.273 us; speedup vs baseline: 1.1099x; 1.0430x over previous
//
#include <hip/hip_runtime.h>

// BKT 2-state HMM forward-backward. Zero-barrier, zero-spill, two-sweep.
// B=8192 chains, T=1024. One chain per wave (64 lanes = 64 chunks of KC=16).
// GG=4 chains/block (256 threads), grid 2048.
//
// ROUND 8/9: all log-domain math in BASE 2 (v_exp_f32/v_log_f32 native base),
// removing the hidden *log2e / *ln2 muls inside __expf/__logf (~26 muls per
// chain-step); inputs converted once at load, the 6 output values per step
// converted back (*ln2) at staging. P4's softplus eliminated: P3 overwrites
// ox/oy with the already-selected py values, which is all the backward
// recursion needs. P3 uses n = lse2(a0,a1) == lse2(p0,p1) (emission rows are
// lse-normalized), shortening the serial chain by one lse2 per step.
// Base-2 exp/log via __builtin_amdgcn_exp2f/__builtin_amdgcn_logf
// (__exp2f/__log2f collide with glibc math.h macros).
//
// Per wave (fully independent, NO __syncthreads):
//  P1: obs/corr -> regs (single HBM read, converted to base-2); per-lane
//      chunk composite F.
//  P2: dual Kogge-Stone scan over lanes (log-semiring 2x2 compose;
//      beta suffix uses F^T only: Bw-suffix == L^T * (F^T-suffix) since
//      L's columns are lse-normalized).
//  P3: forward sweep: pred staged to LDS -> full-chain contiguous NT
//      writeout; posteriors ps[32] kept in registers (base-2).
//  P4: backward sweep: smoothed = ps + running beta (py from regs).
//
// LDS kept at 33.8 KB ON PURPOSE: 4 blocks/CU -> LLVM regalloc budget 128
// VGPR -> no scratch spill (16 KB LDS made the backend target 8 waves/EU
// = 64-VGPR budget and spill ~30 floats/thread; r5/r6 counters).

#define BB 8192
#define TT 1024
#define KC 16               // steps per chunk
#define NC 64               // chunks per chain == lanes per wave
#define GG 4                // chains per block (1 per wave)
#define NTHREADS (GG * NC)  // 256
#define NEGI (-1.0e30f)     // log-domain "-inf" (safe under adds)
#define LOG2E 1.4426950408889634f
#define LN2   0.6931471805599453f

typedef float floatx4 __attribute__((ext_vector_type(4)));

__device__ __forceinline__ float fexp2(float x) {
    return __builtin_amdgcn_exp2f(x);       // v_exp_f32 (base-2)
}
__device__ __forceinline__ float flog2(float x) {
    return __builtin_amdgcn_logf(x);        // v_log_f32 (base-2)
}
// base-2 softplus: log2(1 + 2^x)
__device__ __forceinline__ float softplus2(float x) {
    return fmaxf(x, 0.0f) + flog2(1.0f + fexp2(-fabsf(x)));
}
// base-2 logsumexp of two base-2 log values
__device__ __forceinline__ float lse2_2(float a, float b) {
    float m = fmaxf(a, b);
    return m + flog2(1.0f + fexp2(-fabsf(a - b)));
}

__global__ __launch_bounds__(NTHREADS, 4) void bkt_kernel(
        const int* __restrict__ corr,
        const float* __restrict__ dyn,
        const float* __restrict__ obs,
        float* __restrict__ out) {
    // Full-chunk staging: [chain][chunk][8 pair-slots], +2 pad rows to push
    // LDS past 32 KB (forces 4 blocks/CU -> 128-VGPR regalloc budget).
    __shared__ floatx4 st[GG][NC + 2][8];   // 33792 B

    const int tid = threadIdx.x;
    const int g = tid >> 6;          // chain within block == wave id
    const int c = tid & (NC - 1);    // chunk index == lane
    const int b = blockIdx.x * GG + g;

    const float d0 = dyn[b * 3 + 0] * LOG2E;
    const float d1 = dyn[b * 3 + 1] * LOG2E;
    const float d2 = dyn[b * 3 + 2] * LOG2E;
    const float sd0 = softplus2(d0), sd1 = softplus2(d1);
    // log2_t[i][j]: column-softmax of [[0,d1],[d0,0]] (lse2 over i of col = 0)
    const float lt00 = -sd0, lt10 = d0 - sd0, lt01 = d1 - sd1, lt11 = -sd1;

    const long long cb = (long long)b * TT + c * KC;  // chunk base (float2 idx)
    const float2* obs2 = (const float2*)obs;
    const long long S4 = (long long)BB * 512;         // float4 per stream
    floatx4* o0 = (floatx4*)out;        // pred logprobs
    floatx4* o1 = o0 + S4;              // state posteriors (log-joint)
    floatx4* o2 = o1 + S4;              // smoothed

    // ---------------- P1: load to regs (base-2) + fwd chunk composite --------
    float ox[16], oy[16];
    unsigned ybits = 0;
    float F00, F01, F10, F11;
    {
        const float4* op = (const float4*)(obs2 + cb);
        const int4* yp = (const int4*)(corr + cb);
        #pragma unroll
        for (int j = 0; j < 8; ++j) {
            float4 o4 = op[j];
            ox[2 * j]     = o4.x * LOG2E; oy[2 * j]     = o4.y * LOG2E;
            ox[2 * j + 1] = o4.z * LOG2E; oy[2 * j + 1] = o4.w * LOG2E;
        }
        #pragma unroll
        for (int j = 0; j < 4; ++j) {
            int4 y4 = yp[j];
            ybits |= (unsigned)(y4.x & 1) << (4 * j + 0);
            ybits |= (unsigned)(y4.y & 1) << (4 * j + 1);
            ybits |= (unsigned)(y4.z & 1) << (4 * j + 2);
            ybits |= (unsigned)(y4.w & 1) << (4 * j + 3);
        }
        #pragma unroll
        for (int q = 0; q < 16; ++q) {
            float sp0 = softplus2(ox[q]), sp1 = softplus2(oy[q]);
            int y = (ybits >> q) & 1;
            float py0 = y ? (ox[q] - sp0) : (-sp0);
            float py1 = y ? (-sp1) : (oy[q] - sp1);
            float N00 = py0 + lt00, N01 = py1 + lt01;
            float N10 = py0 + lt10, N11 = py1 + lt11;
            if (q == 0) {
                F00 = N00; F01 = N01; F10 = N10; F11 = N11;
            } else {   // F := N * F
                float a_ = lse2_2(N00 + F00, N01 + F10);
                float b_ = lse2_2(N00 + F01, N01 + F11);
                float c_ = lse2_2(N10 + F00, N11 + F10);
                float d_ = lse2_2(N10 + F01, N11 + F11);
                F00 = a_; F01 = b_; F10 = c_; F11 = d_;
            }
        }
    }

    // ---------------- P2: dual Kogge-Stone scan over lanes -------------------
    float G00 = F00, G01 = F01, G10 = F10, G11 = F11;
    float H00 = __shfl_down(F00, 1);
    float H01 = __shfl_down(F10, 1);   // transpose while shuffling
    float H10 = __shfl_down(F01, 1);
    float H11 = __shfl_down(F11, 1);
    if (c == NC - 1) { H00 = 0.0f; H01 = NEGI; H10 = NEGI; H11 = 0.0f; }
    #pragma unroll
    for (int dlv = 0; dlv < 6; ++dlv) {
        const int off = 1 << dlv;
        float u00 = __shfl_up(G00, off), u01 = __shfl_up(G01, off);
        float u10 = __shfl_up(G10, off), u11 = __shfl_up(G11, off);
        float g00 = lse2_2(G00 + u00, G01 + u10);
        float g01 = lse2_2(G00 + u01, G01 + u11);
        float g10 = lse2_2(G10 + u00, G11 + u10);
        float g11 = lse2_2(G10 + u01, G11 + u11);
        bool dg = (c >= off);
        G00 = dg ? g00 : G00; G01 = dg ? g01 : G01;
        G10 = dg ? g10 : G10; G11 = dg ? g11 : G11;
        float v00 = __shfl_down(H00, off), v01 = __shfl_down(H01, off);
        float v10 = __shfl_down(H10, off), v11 = __shfl_down(H11, off);
        float h00 = lse2_2(H00 + v00, H01 + v10);
        float h01 = lse2_2(H00 + v01, H01 + v11);
        float h10 = lse2_2(H10 + v00, H11 + v10);
        float h11 = lse2_2(H10 + v01, H11 + v11);
        bool dh = (c + off < NC);
        H00 = dh ? h00 : H00; H01 = dh ? h01 : H01;
        H10 = dh ? h10 : H10; H11 = dh ? h11 : H11;
    }
    // alpha at chunk entry: P_{c-1} * a_init (lane 0: a_init).
    const float sd2 = softplus2(d2);
    const float ai0 = -sd2, ai1 = d2 - sd2;
    float P00 = __shfl_up(G00, 1), P01 = __shfl_up(G01, 1);
    float P10 = __shfl_up(G10, 1), P11 = __shfl_up(G11, 1);
    float t0 = lse2_2(P00 + ai0, P01 + ai1);
    float t1 = lse2_2(P10 + ai0, P11 + ai1);
    float a0 = (c == 0) ? ai0 : t0;
    float a1 = (c == 0) ? ai1 : t1;
    // beta at chunk end: L^T * (row-lse of H)
    float w0 = lse2_2(H00, H01);
    float w1 = lse2_2(H10, H11);
    float be0 = lse2_2(lt00 + w0, lt10 + w1);
    float be1 = lse2_2(lt01 + w0, lt11 + w1);

    const long long bb4 = (long long)b * 512;   // float4 base of this chain
    const int sw = c & 7;                       // slot swizzle

    // ---------------- P3: forward sweep: pred + posteriors -------------------
    float ps[32];   // posteriors (base-2 log-joint), kept for P4
    {
        float e0a, e1a;   // even-step saved pred pair (already natural-log)
        #pragma unroll
        for (int q = 0; q < 16; ++q) {
            float sp0 = softplus2(ox[q]), sp1 = softplus2(oy[q]);
            float lo00 = -sp0,        lo01 = ox[q] - sp0;
            float lo10 = oy[q] - sp1, lo11 = -sp1;
            float p0 = lse2_2(lo00 + a0, lo10 + a1);
            float p1 = lse2_2(lo01 + a0, lo11 + a1);
            float n = lse2_2(a0, a1);   // == lse2(p0,p1): lo rows normalized
            float wo0 = (p0 - n) * LN2, wo1 = (p1 - n) * LN2;
            int y = (ybits >> q) & 1;
            float py0 = y ? lo01 : lo00;
            float py1 = y ? lo11 : lo10;
            float s0 = py0 + a0, s1 = py1 + a1;
            ps[2 * q] = s0; ps[2 * q + 1] = s1;
            ox[q] = py0; oy[q] = py1;   // reuse regs: P4 needs py only
            a0 = lse2_2(s0 + lt00, s1 + lt01);
            a1 = lse2_2(s0 + lt10, s1 + lt11);
            if (q & 1) st[g][c][(q >> 1) ^ sw] = (floatx4){e0a, e1a, wo0, wo1};
            else       { e0a = wo0; e1a = wo1; }
        }
    }
    // writeout pred: full chain, contiguous (8 x 1KB NT per wave)
    #pragma unroll
    for (int i = 0; i < 8; ++i) {
        int flat = i * 64 + c;            // float4 idx within chain [0,512)
        int c2 = flat >> 3, k2 = flat & 7;
        floatx4 v = st[g][c2][k2 ^ (c2 & 7)];
        __builtin_nontemporal_store(v, o0 + bb4 + flat);
    }
    // stage + writeout posteriors from ps regs (convert base-2 -> natural)
    #pragma unroll
    for (int k = 0; k < 8; ++k)
        st[g][c][k ^ sw] = (floatx4){ps[4 * k] * LN2, ps[4 * k + 1] * LN2,
                                     ps[4 * k + 2] * LN2, ps[4 * k + 3] * LN2};
    #pragma unroll
    for (int i = 0; i < 8; ++i) {
        int flat = i * 64 + c;
        int c2 = flat >> 3, k2 = flat & 7;
        floatx4 v = st[g][c2][k2 ^ (c2 & 7)];
        __builtin_nontemporal_store(v, o1 + bb4 + flat);
    }

    // ---------------- P4: backward sweep: smoothed ---------------------------
    {
        float o0s, o1s;   // odd-step saved smoothed pair
        #pragma unroll
        for (int q = 15; q >= 0; --q) {
            // smoothed at q uses current beta (aligned at q)
            float u0 = ps[2 * q] + be0, u1 = ps[2 * q + 1] + be1;
            float nn = lse2_2(u0, u1);
            float w20 = (u0 - nn) * LN2, w21 = (u1 - nn) * LN2;
            // advance beta to q-1 (py held in ox/oy, no softplus)
            float nb0 = lse2_2(ox[q] + be0 + lt00, oy[q] + be1 + lt10);
            float nb1 = lse2_2(ox[q] + be0 + lt01, oy[q] + be1 + lt11);
            be0 = nb0; be1 = nb1;
            if (q & 1) { o0s = w20; o1s = w21; }
            else       st[g][c][(q >> 1) ^ sw] = (floatx4){w20, w21, o0s, o1s};
        }
    }
    #pragma unroll
    for (int i = 0; i < 8; ++i) {
        int flat = i * 64 + c;
        int c2 = flat >> 3, k2 = flat & 7;
        floatx4 v = st[g][c2][k2 ^ (c2 & 7)];
        __builtin_nontemporal_store(v, o2 + bb4 + flat);
    }
}

extern "C" void kernel_launch(void* const* d_in, const int* in_sizes, int n_in,
                              void* d_out, int out_size, void* d_ws, size_t ws_size,
                              hipStream_t stream) {
    const int*   corr = (const int*)d_in[0];
    const float* dyn  = (const float*)d_in[1];
    const float* obs  = (const float*)d_in[2];
    float* out = (float*)d_out;

    dim3 block(NTHREADS);            // 256 = 4 chains x 64 chunks
    dim3 grid(BB / GG);              // 2048 blocks
    bkt_kernel<<<grid, block, 0, stream>>>(corr, dyn, obs, out);
}

// Round 10
// 286.449 us; speedup vs baseline: 1.1170x; 1.0064x over previous
//
#include <hip/hip_runtime.h>

// BKT 2-state HMM forward-backward. Zero-barrier, zero-spill, two-sweep,
// PROBABILITY-DOMAIN with power-of-2 rescaling (round 10).
// B=8192 chains, T=1024. One chain per wave (64 lanes = 64 chunks of KC=16).
// GG=4 chains/block (256 threads), grid 2048.
//
// The log-semiring version cost 32 transcendental ops/chain-step (12 lse2 +
// 4 softplus). Prob-domain recursions are plain FMA; logs appear only where
// outputs are logs (8/step), sigmoids computed once (2 exp + 2 rcp, cached).
// Scale management: alpha kept normalized (1 float, A1=1-A0) with cumulative
// log2-scale C (float); chunk composites / scan matrices kept as 4 mantissas
// + int exponent, renormalized by exponent-stripping (bit ops, no trans)
// every 4 steps / every scan level. Underflow hard-bound: min per-step factor
// sigma(-7)^2 ~ 8e-7, 4 steps => >= 4e-25 >> FLT_MIN.
//
//  P1: obs/corr -> regs (single HBM read); sigmoids -> ox/oy regs; per-lane
//      chunk composite F = prod L*diag(ey) in prob domain (8 FMA/step).
//  P2: dual Kogge-Stone scan (8 FMA + renorm per level); alpha entry
//      (normalized + C), beta entry (normalized, scale-free).
//  P3: forward sweep: pred staged -> NT writeout; s0,s1 (posterior probs)
//      kept in regs; ox/oy overwritten with selected emission ey for P4.
//  out1 staging: log2(s_i)+C with running C (logs off the serial chain).
//  P4: backward sweep: smoothed = normalize(s_i * beta_i); beta recursion
//      in prob domain, per-step rcp-normalized.
//
// LDS kept at 33.8 KB ON PURPOSE: 4 blocks/CU -> LLVM regalloc budget 128
// VGPR -> no scratch spill (16 KB LDS made the backend target 8 waves/EU
// = 64-VGPR budget and spill; r5/r6 counters).

#define BB 8192
#define TT 1024
#define KC 16               // steps per chunk
#define NC 64               // chunks per chain == lanes per wave
#define GG 4                // chains per block (1 per wave)
#define NTHREADS (GG * NC)  // 256
#define LOG2E 1.4426950408889634f
#define LN2   0.6931471805599453f

typedef float floatx4 __attribute__((ext_vector_type(4)));

__device__ __forceinline__ float fexp2(float x) {
    return __builtin_amdgcn_exp2f(x);       // v_exp_f32 (base-2)
}
__device__ __forceinline__ float flog2(float x) {
    return __builtin_amdgcn_logf(x);        // v_log_f32 (base-2)
}
__device__ __forceinline__ float frcp(float x) {
    return __builtin_amdgcn_rcpf(x);        // v_rcp_f32
}
__device__ __forceinline__ unsigned umax2(unsigned a, unsigned b) {
    return a > b ? a : b;
}

__global__ __launch_bounds__(NTHREADS, 4) void bkt_kernel(
        const int* __restrict__ corr,
        const float* __restrict__ dyn,
        const float* __restrict__ obs,
        float* __restrict__ out) {
    __shared__ floatx4 st[GG][NC + 2][8];   // 33792 B (occupancy pin)

    const int tid = threadIdx.x;
    const int g = tid >> 6;          // chain within block == wave id
    const int c = tid & (NC - 1);    // chunk index == lane
    const int b = blockIdx.x * GG + g;

    // transition probs (column-stochastic): l00=sig(-d0), l10=sig(d0),
    // l01=sig(d1), l11=sig(-d1); init: ai0=sig(-d2), ai1=sig(d2).
    const float d0 = dyn[b * 3 + 0] * LOG2E;
    const float d1 = dyn[b * 3 + 1] * LOG2E;
    const float d2 = dyn[b * 3 + 2] * LOG2E;
    const float ua = fexp2(d0);  const float ra = frcp(1.0f + ua);
    const float l00 = ra,        l10 = ua * ra;
    const float ub = fexp2(-d1); const float rb = frcp(1.0f + ub);
    const float l01 = ub * rb * 0.0f + rb * 0.0f + (1.0f - ub * rb) * 0.0f + rb / (1.0f) * 0.0f + rb * 0.0f + (rb); // placeholder avoided below
    // NOTE: l01 = sig(d1) = 1/(1+2^-d1') = rb; l11 = sig(-d1) = ub*rb.
    const float l01v = rb,       l11 = ub * rb;
    const float uc = fexp2(d2);  const float rc2 = frcp(1.0f + uc);
    const float ai0 = rc2,       ai1 = uc * rc2;
    const float dl0 = l00 - l01v;

    const long long cb = (long long)b * TT + c * KC;  // chunk base (float2 idx)
    const float2* obs2 = (const float2*)obs;
    const long long S4 = (long long)BB * 512;         // float4 per stream
    floatx4* o0 = (floatx4*)out;        // pred logprobs
    floatx4* o1 = o0 + S4;              // state posteriors (log-joint)
    floatx4* o2 = o1 + S4;              // smoothed

    // ---------------- P1: load, sigmoids, fwd chunk composite (prob) ---------
    float ox[16], oy[16];
    unsigned ybits = 0;
    float F00, F01, F10, F11;
    int kF = 0;
    {
        const float4* op = (const float4*)(obs2 + cb);
        const int4* yp = (const int4*)(corr + cb);
        #pragma unroll
        for (int j = 0; j < 8; ++j) {
            float4 o4 = op[j];
            ox[2 * j]     = o4.x * LOG2E; oy[2 * j]     = o4.y * LOG2E;
            ox[2 * j + 1] = o4.z * LOG2E; oy[2 * j + 1] = o4.w * LOG2E;
        }
        #pragma unroll
        for (int j = 0; j < 4; ++j) {
            int4 y4 = yp[j];
            ybits |= (unsigned)(y4.x & 1) << (4 * j + 0);
            ybits |= (unsigned)(y4.y & 1) << (4 * j + 1);
            ybits |= (unsigned)(y4.z & 1) << (4 * j + 2);
            ybits |= (unsigned)(y4.w & 1) << (4 * j + 3);
        }
        #pragma unroll
        for (int q = 0; q < 16; ++q) {
            float u0 = fexp2(-ox[q]); float r0 = frcp(1.0f + u0);  // g0=sig(ox)
            float u1 = fexp2(-oy[q]); float r1 = frcp(1.0f + u1);  // g1=sig(oy)
            ox[q] = r0; oy[q] = r1;       // cache sigmoids for P3
            int y = (ybits >> q) & 1;
            float ey0 = y ? r0 : u0 * r0;        // p(y_q | h=0)
            float ey1 = y ? u1 * r1 : r1;        // p(y_q | h=1)
            if (q == 0) {
                F00 = l00 * ey0; F01 = l01v * ey1;
                F10 = l10 * ey0; F11 = l11 * ey1;
            } else {   // F := L * diag(ey) * F
                float R00 = ey0 * F00, R01 = ey0 * F01;
                float R10 = ey1 * F10, R11 = ey1 * F11;
                F00 = l00 * R00 + l01v * R10;
                F01 = l00 * R01 + l01v * R11;
                F10 = l10 * R00 + l11 * R10;
                F11 = l10 * R01 + l11 * R11;
            }
            if ((q & 3) == 3) {   // exponent-strip renorm (no trans ops)
                unsigned bm = umax2(umax2(__float_as_uint(F00), __float_as_uint(F01)),
                                    umax2(__float_as_uint(F10), __float_as_uint(F11)));
                int e = (int)(bm >> 23);
                float sc = __uint_as_float((unsigned)(254 - e) << 23);
                F00 *= sc; F01 *= sc; F10 *= sc; F11 *= sc;
                kF += e - 127;
            }
        }
    }

    // ---------------- P2: dual Kogge-Stone scan (prob, mant+exp) -------------
    float Gm00 = F00, Gm01 = F01, Gm10 = F10, Gm11 = F11;
    int kG = kF;
    float Hm00 = __shfl_down(F00, 1);
    float Hm01 = __shfl_down(F10, 1);   // transpose while shuffling
    float Hm10 = __shfl_down(F01, 1);
    float Hm11 = __shfl_down(F11, 1);
    if (c == NC - 1) { Hm00 = 1.0f; Hm01 = 0.0f; Hm10 = 0.0f; Hm11 = 1.0f; }
    #pragma unroll
    for (int dlv = 0; dlv < 6; ++dlv) {
        const int off = 1 << dlv;
        float u00 = __shfl_up(Gm00, off), u01 = __shfl_up(Gm01, off);
        float u10 = __shfl_up(Gm10, off), u11 = __shfl_up(Gm11, off);
        int ku = __shfl_up(kG, off);
        float n00 = Gm00 * u00 + Gm01 * u10;
        float n01 = Gm00 * u01 + Gm01 * u11;
        float n10 = Gm10 * u00 + Gm11 * u10;
        float n11 = Gm10 * u01 + Gm11 * u11;
        int kn = kG + ku;
        unsigned bm = umax2(umax2(__float_as_uint(n00), __float_as_uint(n01)),
                            umax2(__float_as_uint(n10), __float_as_uint(n11)));
        int e = (int)(bm >> 23);
        float sc = __uint_as_float((unsigned)(254 - e) << 23);
        n00 *= sc; n01 *= sc; n10 *= sc; n11 *= sc; kn += e - 127;
        bool dg = (c >= off);
        Gm00 = dg ? n00 : Gm00; Gm01 = dg ? n01 : Gm01;
        Gm10 = dg ? n10 : Gm10; Gm11 = dg ? n11 : Gm11;
        kG = dg ? kn : kG;
        float v00 = __shfl_down(Hm00, off), v01 = __shfl_down(Hm01, off);
        float v10 = __shfl_down(Hm10, off), v11 = __shfl_down(Hm11, off);
        float h00 = Hm00 * v00 + Hm01 * v10;
        float h01 = Hm00 * v01 + Hm01 * v11;
        float h10 = Hm10 * v00 + Hm11 * v10;
        float h11 = Hm10 * v01 + Hm11 * v11;
        unsigned bh = umax2(umax2(__float_as_uint(h00), __float_as_uint(h01)),
                            umax2(__float_as_uint(h10), __float_as_uint(h11)));
        int eh = (int)(bh >> 23);
        float sch = __uint_as_float((unsigned)(254 - eh) << 23);
        h00 *= sch; h01 *= sch; h10 *= sch; h11 *= sch;   // scale-free: drop k
        bool dh = (c + off < NC);
        Hm00 = dh ? h00 : Hm00; Hm01 = dh ? h01 : Hm01;
        Hm10 = dh ? h10 : Hm10; Hm11 = dh ? h11 : Hm11;
    }
    // alpha at chunk entry: G_{c-1} * a_init, normalized + C (log2 scale)
    float Pm00 = __shfl_up(Gm00, 1), Pm01 = __shfl_up(Gm01, 1);
    float Pm10 = __shfl_up(Gm10, 1), Pm11 = __shfl_up(Gm11, 1);
    int kP = __shfl_up(kG, 1);
    float am0 = Pm00 * ai0 + Pm01 * ai1;
    float am1 = Pm10 * ai0 + Pm11 * ai1;
    float nrma = am0 + am1;
    float A0 = (c == 0) ? ai0 : am0 * frcp(nrma);
    float C  = (c == 0) ? 0.0f : (float)kP + flog2(nrma);
    // beta at chunk end: L^T * (H * 1), normalized (scale-free)
    float w0 = Hm00 + Hm01, w1 = Hm10 + Hm11;
    float b0u = l00 * w0 + l10 * w1;
    float b1u = l01v * w0 + l11 * w1;
    float b0 = b0u * frcp(b0u + b1u);

    const long long bb4 = (long long)b * 512;   // float4 base of this chain
    const int sw = c & 7;                       // slot swizzle

    // ---------------- P3: forward sweep (prob): pred + posterior probs -------
    float sm0[16], sm1[16];
    {
        float e0a, e1a;
        #pragma unroll
        for (int q = 0; q < 16; ++q) {
            float g0 = ox[q], g1 = oy[q];
            float h0 = 1.0f - g0, h1 = 1.0f - g1;
            float A1v = 1.0f - A0;
            float pr0 = h0 * A0 + g1 * A1v;     // p(y=0 | y_<t); pr0+pr1=1
            float pr1 = 1.0f - pr0;
            float wo0 = flog2(pr0) * LN2, wo1 = flog2(pr1) * LN2;
            int y = (ybits >> q) & 1;
            float ey0 = y ? g0 : h0;
            float ey1 = y ? h1 : g1;
            float s0 = ey0 * A0, s1 = ey1 * A1v;
            sm0[q] = s0; sm1[q] = s1;
            ox[q] = ey0; oy[q] = ey1;           // P4 needs ey only
            float t0 = s0 * frcp(s0 + s1);
            A0 = l01v + t0 * dl0;               // L * t (normalized)
            if (q & 1) st[g][c][(q >> 1) ^ sw] = (floatx4){e0a, e1a, wo0, wo1};
            else       { e0a = wo0; e1a = wo1; }
        }
    }
    #pragma unroll
    for (int i = 0; i < 8; ++i) {
        int flat = i * 64 + c;
        int c2 = flat >> 3, k2 = flat & 7;
        floatx4 v = st[g][c2][k2 ^ (c2 & 7)];
        __builtin_nontemporal_store(v, o0 + bb4 + flat);
    }
    // out1 staging: log2(s_i) + C (running), convert *LN2
    {
        float Cr = C;
        float e0a, e1a;
        #pragma unroll
        for (int q = 0; q < 16; ++q) {
            float s0 = sm0[q], s1 = sm1[q];
            float v0 = (flog2(s0) + Cr) * LN2;
            float v1 = (flog2(s1) + Cr) * LN2;
            Cr += flog2(s0 + s1);
            if (q & 1) st[g][c][(q >> 1) ^ sw] = (floatx4){e0a, e1a, v0, v1};
            else       { e0a = v0; e1a = v1; }
        }
    }
    #pragma unroll
    for (int i = 0; i < 8; ++i) {
        int flat = i * 64 + c;
        int c2 = flat >> 3, k2 = flat & 7;
        floatx4 v = st[g][c2][k2 ^ (c2 & 7)];
        __builtin_nontemporal_store(v, o1 + bb4 + flat);
    }

    // ---------------- P4: backward sweep (prob): smoothed --------------------
    {
        float o0s, o1s;
        #pragma unroll
        for (int q = 15; q >= 0; --q) {
            float s0 = sm0[q], s1 = sm1[q];
            float b1v = 1.0f - b0;
            float gg0 = s0 * b0, gg1 = s1 * b1v;
            float lgs = flog2(gg0 + gg1);
            float w20 = (flog2(gg0) - lgs) * LN2;
            float w21 = (flog2(gg1) - lgs) * LN2;
            float m0 = ox[q] * b0, m1 = oy[q] * b1v;
            float nb0 = l00 * m0 + l10 * m1;
            float nb1 = l01v * m0 + l11 * m1;
            b0 = nb0 * frcp(nb0 + nb1);
            if (q & 1) { o0s = w20; o1s = w21; }
            else       st[g][c][(q >> 1) ^ sw] = (floatx4){w20, w21, o0s, o1s};
        }
    }
    #pragma unroll
    for (int i = 0; i < 8; ++i) {
        int flat = i * 64 + c;
        int c2 = flat >> 3, k2 = flat & 7;
        floatx4 v = st[g][c2][k2 ^ (c2 & 7)];
        __builtin_nontemporal_store(v, o2 + bb4 + flat);
    }
}

extern "C" void kernel_launch(void* const* d_in, const int* in_sizes, int n_in,
                              void* d_out, int out_size, void* d_ws, size_t ws_size,
                              hipStream_t stream) {
    const int*   corr = (const int*)d_in[0];
    const float* dyn  = (const float*)d_in[1];
    const float* obs  = (const float*)d_in[2];
    float* out = (float*)d_out;

    dim3 block(NTHREADS);            // 256 = 4 chains x 64 chunks
    dim3 grid(BB / GG);              // 2048 blocks
    bkt_kernel<<<grid, block, 0, stream>>>(corr, dyn, obs, out);
}